// Round 2
// baseline (242.009 us; speedup 1.0000x reference)
//
#include <hip/hip_runtime.h>
#include <hip/hip_bf16.h>
#include <math.h>

// NNUE-style sparse feature transform + output head, one block per batch row.
// FT=512 columns, 128 threads * float4 = 512 cols per iteration.
// batch_ids sorted -> binary search segment bounds (broadcast, divergence-free).

constexpr int FT      = 512;
constexpr int FV      = 768;
constexpr int THREADS = 128;
constexpr int CHUNK   = 128;   // LDS staging chunk of segment entries

__global__ __launch_bounds__(THREADS)
void nnue_kernel(const float* __restrict__ values,
                 const float* __restrict__ W_ft,
                 const float* __restrict__ ft_b,
                 const float* __restrict__ W_fft,
                 const float* __restrict__ fft_b,
                 const float* __restrict__ W_out,
                 const float* __restrict__ out_b,
                 const int*   __restrict__ batch_ids,
                 const int*   __restrict__ stm_feat,
                 const int*   __restrict__ nstm_feat,
                 int nnz,
                 float* __restrict__ out)
{
    const int b   = blockIdx.x;
    const int t   = threadIdx.x;
    const int col = t * 4;

    // ---- segment bounds via lower_bound on sorted batch_ids ----
    // All lanes search identical keys -> broadcast loads, no divergence.
    int lo0 = 0, hi0 = nnz;          // lower_bound(b)
    while (lo0 < hi0) {
        int mid = (lo0 + hi0) >> 1;
        if (batch_ids[mid] < b) lo0 = mid + 1; else hi0 = mid;
    }
    int lo1 = lo0, hi1 = nnz;        // lower_bound(b+1), start from lo0
    while (lo1 < hi1) {
        int mid = (lo1 + hi1) >> 1;
        if (batch_ids[mid] < b + 1) lo1 = mid + 1; else hi1 = mid;
    }
    const int seg_lo = lo0, seg_hi = lo1;

    __shared__ int   sh_off_s [CHUNK];  // stm  W_ft row offset
    __shared__ int   sh_off_sv[CHUNK];  // stm  W_fft row offset
    __shared__ int   sh_off_n [CHUNK];  // nstm W_ft row offset
    __shared__ int   sh_off_nv[CHUNK];  // nstm W_fft row offset
    __shared__ float sh_v     [CHUNK];

    float4 acc_s = make_float4(0.f, 0.f, 0.f, 0.f);
    float4 acc_n = make_float4(0.f, 0.f, 0.f, 0.f);

    for (int base = seg_lo; base < seg_hi; base += CHUNK) {
        const int cnt = min(CHUNK, seg_hi - base);
        __syncthreads();
        if (t < cnt) {
            int fs = stm_feat[base + t];
            int fn = nstm_feat[base + t];
            sh_off_s [t] = fs * FT;
            sh_off_sv[t] = (fs % FV) * FT;
            sh_off_n [t] = fn * FT;
            sh_off_nv[t] = (fn % FV) * FT;
            sh_v     [t] = values[base + t];
        }
        __syncthreads();

        #pragma unroll 2
        for (int j = 0; j < cnt; ++j) {
            const int   os  = sh_off_s [j];
            const int   osv = sh_off_sv[j];
            const int   on  = sh_off_n [j];
            const int   onv = sh_off_nv[j];
            const float v   = sh_v[j];

            const float4 a  = *(const float4*)(W_ft  + os  + col);
            const float4 av = *(const float4*)(W_fft + osv + col);
            const float4 c  = *(const float4*)(W_ft  + on  + col);
            const float4 cv = *(const float4*)(W_fft + onv + col);

            acc_s.x = fmaf(a.x + av.x, v, acc_s.x);
            acc_s.y = fmaf(a.y + av.y, v, acc_s.y);
            acc_s.z = fmaf(a.z + av.z, v, acc_s.z);
            acc_s.w = fmaf(a.w + av.w, v, acc_s.w);
            acc_n.x = fmaf(c.x + cv.x, v, acc_n.x);
            acc_n.y = fmaf(c.y + cv.y, v, acc_n.y);
            acc_n.z = fmaf(c.z + cv.z, v, acc_n.z);
            acc_n.w = fmaf(c.w + cv.w, v, acc_n.w);
        }
    }

    // ---- epilogue: bias, clip[0,1], fused dot with W_out ----
    const float4 fb  = *(const float4*)(ft_b  + col);
    const float4 vb  = *(const float4*)(fft_b + col);
    const float4 wos = *(const float4*)(W_out + col);        // stm half
    const float4 won = *(const float4*)(W_out + FT + col);   // nstm half

    float partial = 0.f;
    {
        float h;
        h = fminf(fmaxf(acc_s.x + fb.x + vb.x, 0.f), 1.f); partial = fmaf(h, wos.x, partial);
        h = fminf(fmaxf(acc_s.y + fb.y + vb.y, 0.f), 1.f); partial = fmaf(h, wos.y, partial);
        h = fminf(fmaxf(acc_s.z + fb.z + vb.z, 0.f), 1.f); partial = fmaf(h, wos.z, partial);
        h = fminf(fmaxf(acc_s.w + fb.w + vb.w, 0.f), 1.f); partial = fmaf(h, wos.w, partial);
        h = fminf(fmaxf(acc_n.x + fb.x + vb.x, 0.f), 1.f); partial = fmaf(h, won.x, partial);
        h = fminf(fmaxf(acc_n.y + fb.y + vb.y, 0.f), 1.f); partial = fmaf(h, won.y, partial);
        h = fminf(fmaxf(acc_n.z + fb.z + vb.z, 0.f), 1.f); partial = fmaf(h, won.z, partial);
        h = fminf(fmaxf(acc_n.w + fb.w + vb.w, 0.f), 1.f); partial = fmaf(h, won.w, partial);
    }

    // wave (64-lane) shuffle reduction, then cross-wave via LDS
    #pragma unroll
    for (int off = 32; off > 0; off >>= 1)
        partial += __shfl_down(partial, off, 64);

    __shared__ float wave_sum[THREADS / 64];
    if ((t & 63) == 0) wave_sum[t >> 6] = partial;
    __syncthreads();
    if (t == 0) {
        float s = wave_sum[0] + wave_sum[1] + out_b[0];
        out[b] = 1.0f / (1.0f + expf(-s));
    }
}

extern "C" void kernel_launch(void* const* d_in, const int* in_sizes, int n_in,
                              void* d_out, int out_size, void* d_ws, size_t ws_size,
                              hipStream_t stream) {
    const float* values    = (const float*)d_in[0];
    const float* W_ft      = (const float*)d_in[1];
    const float* ft_b      = (const float*)d_in[2];
    const float* W_fft     = (const float*)d_in[3];
    const float* fft_b     = (const float*)d_in[4];
    const float* W_out     = (const float*)d_in[5];
    const float* out_b     = (const float*)d_in[6];
    const int*   batch_ids = (const int*)d_in[7];
    const int*   stm_feat  = (const int*)d_in[8];
    const int*   nstm_feat = (const int*)d_in[9];

    const int nnz = in_sizes[0];
    const int B   = out_size;   // (B,1) f32 output

    nnue_kernel<<<B, THREADS, 0, stream>>>(
        values, W_ft, ft_b, W_fft, fft_b, W_out, out_b,
        batch_ids, stm_feat, nstm_feat, nnz, (float*)d_out);
}